// Round 9
// baseline (251.017 us; speedup 1.0000x reference)
//
#include <hip/hip_runtime.h>
#include <hip/hip_bf16.h>

#define B_ 4
#define T_ 2048
#define E_ 1024
#define H_ 16
#define D_ 64
#define M_ (B_*T_)   // 8192 rows

typedef short bf16x8 __attribute__((ext_vector_type(8)));
typedef float f32x4  __attribute__((ext_vector_type(4)));
typedef float f32x16 __attribute__((ext_vector_type(16)));

__device__ __forceinline__ short f2bf(float f) {
    __hip_bfloat16 h = __float2bfloat16(f);
    return *reinterpret_cast<short*>(&h);
}

__device__ __forceinline__ void async_ld16(const void* g, void* l) {
    __builtin_amdgcn_global_load_lds(
        (const __attribute__((address_space(1))) unsigned int*)g,
        (__attribute__((address_space(3))) unsigned int*)l, 16, 0, 0);
}

// ---------------------------------------------------------------------------
// Fused prep kernel (R8, unchanged).
// ---------------------------------------------------------------------------
__global__ __launch_bounds__(256) void prep_fused(
        const float* __restrict__ x,   const float* __restrict__ Wo,
        const float* __restrict__ Wq,  const float* __restrict__ Wk,
        const float* __restrict__ Wv,  const float* __restrict__ mask,
        short* __restrict__ xb, short* __restrict__ Wob,
        short* __restrict__ Wt, float* __restrict__ bias) {
    __shared__ float tile[64][65];
    const int bi  = blockIdx.x;
    const int tid = threadIdx.x;

    if (bi < 9216) {                               // elementwise fp32->bf16
        const float* src = (bi < 8192) ? x : Wo;
        short* dst       = (bi < 8192) ? xb : Wob;
        const int i = ((bi < 8192) ? bi : (bi - 8192)) * 256 + tid;
        float4 v = ((const float4*)src)[i];
        short4 o = make_short4(f2bf(v.x), f2bf(v.y), f2bf(v.z), f2bf(v.w));
        ((short4*)dst)[i] = o;
    } else if (bi < 9984) {                        // weight transpose
        const int idx = bi - 9216;
        const int which = idx >> 8;                // 0..2
        const int h  = (idx & 255) >> 4;
        const int e0 = (idx & 15) * 64;
        const float* __restrict__ W = (which == 0) ? Wq : (which == 1) ? Wk : Wv;
#pragma unroll
        for (int r = 0; r < 4; ++r) {
            int lin = tid + r * 256;
            int er = lin >> 4, c4 = (lin & 15) * 4;
            float4 v = *(const float4*)(W + ((size_t)h * E_ + e0 + er) * D_ + c4);
            tile[er][c4 + 0] = v.x; tile[er][c4 + 1] = v.y;
            tile[er][c4 + 2] = v.z; tile[er][c4 + 3] = v.w;
        }
        __syncthreads();
#pragma unroll
        for (int r = 0; r < 4; ++r) {
            int lin = tid + r * 256;
            int dr = lin >> 4, j4 = (lin & 15) * 4;
            short4 o = make_short4(f2bf(tile[j4 + 0][dr]), f2bf(tile[j4 + 1][dr]),
                                   f2bf(tile[j4 + 2][dr]), f2bf(tile[j4 + 3][dr]));
            *(short4*)(Wt + ((size_t)which * 1024 + h * 64 + dr) * E_ + e0 + j4) = o;
        }
    } else {                                       // bias prep
        const int i = (bi - 9984) * 256 + tid;
        float bm = (1.0f - mask[i]) * -3.402823466e38f;
        bias[i] = fmaf(bm, 1.4426950f, -8.6561700f);
    }
}

// ---------------------------------------------------------------------------
// MFMA GEMM v4 (R8 schedule) + R9: bijective XCD swizzle (T1).
// BK=32, 3 x 24KB LDS buffers -> 2 blocks/CU. Single-barrier counted-vmcnt.
// XCD swizzle: nwg % 8 == 0 for both grids; intra-XCD consecutive blocks
// walk M at fixed n0 -> B-panel (0.25 MB) stays L2-resident per XCD.
// ---------------------------------------------------------------------------
template <int MODE>
__global__ __launch_bounds__(512, 4) void mfma_gemm(
        const short* __restrict__ A,
        const short* __restrict__ Bt,
        short* __restrict__ qo, short* __restrict__ ko, short* __restrict__ vo,
        float* __restrict__ Cout, const float* __restrict__ bo) {
    __shared__ __align__(16) char lds[3 * 24576];   // 72 KiB -> 2 blocks/CU

    const int tid  = threadIdx.x;
    const int wave = tid >> 6, lane = tid & 63;
    const int c = lane & 15, quad = lane >> 4;
    const int wm = wave >> 1, wn = wave & 1;        // 4M x 2N

    // T1: bijective XCD swizzle (nwg divisible by 8)
    const int orig = blockIdx.y * gridDim.x + blockIdx.x;
    const int cpx  = (gridDim.x * gridDim.y) >> 3;
    const int swz  = (orig & 7) * cpx + (orig >> 3);
    const int m0 = (swz & 31) * 256;                // gridDim.x == 32
    const int n0 = (swz >> 5) * 128;

    const int ar = tid >> 2;
    const int ag = (tid & 3) ^ ((tid >> 3) & 3);

    int aoff[4], boff[4];
#pragma unroll
    for (int mi = 0; mi < 4; ++mi) {
        int row = wm * 64 + mi * 16 + c;
        aoff[mi] = row * 64 + ((quad ^ ((row >> 1) & 3)) << 4);
    }
#pragma unroll
    for (int ni = 0; ni < 4; ++ni) {
        int row = wn * 64 + ni * 16 + c;
        boff[ni] = 16384 + row * 64 + ((quad ^ ((row >> 1) & 3)) << 4);
    }

    f32x4 acc[4][4] = {};

#define STG(bufb, k0v) do {                                                  \
        async_ld16(A  + (size_t)(m0 + ar) * 1024 + (k0v) + ag * 8,           \
                   lds + (bufb) + wave * 1024);                              \
        async_ld16(A  + (size_t)(m0 + 128 + ar) * 1024 + (k0v) + ag * 8,     \
                   lds + (bufb) + 8192 + wave * 1024);                       \
        async_ld16(Bt + (size_t)(n0 + ar) * 1024 + (k0v) + ag * 8,           \
                   lds + (bufb) + 16384 + wave * 1024);                      \
    } while (0)

    STG(0, 0);
    STG(24576, 32);
    asm volatile("s_waitcnt vmcnt(3)" ::: "memory");   // K-tile 0 landed
    __builtin_amdgcn_s_barrier();

    int rbase = 0;
#pragma unroll 1
    for (int k = 0; k < 32; ++k) {
        const char* rb = lds + rbase;
        const int wbase = (rbase == 0) ? 49152 : rbase - 24576;

        if (k < 30) STG(wbase, (k + 2) * 32);

        bf16x8 a_[4], b_[4];
#pragma unroll
        for (int mi = 0; mi < 4; ++mi)
            a_[mi] = *(const bf16x8*)(rb + aoff[mi]);
#pragma unroll
        for (int ni = 0; ni < 4; ++ni)
            b_[ni] = *(const bf16x8*)(rb + boff[ni]);

        __builtin_amdgcn_s_setprio(1);
#pragma unroll
        for (int mi = 0; mi < 4; ++mi)
#pragma unroll
            for (int ni = 0; ni < 4; ++ni)
                acc[mi][ni] = __builtin_amdgcn_mfma_f32_16x16x32_bf16(
                    a_[mi], b_[ni], acc[mi][ni], 0, 0, 0);
        __builtin_amdgcn_s_setprio(0);

        if (k < 30)       asm volatile("s_waitcnt vmcnt(3)" ::: "memory");
        else if (k == 30) asm volatile("s_waitcnt vmcnt(0)" ::: "memory");
        if (k < 31) __builtin_amdgcn_s_barrier();

        rbase = (rbase == 49152) ? 0 : rbase + 24576;
    }
#undef STG

    if (MODE == 0) {
        const int which = n0 >> 10;
        const int nb = n0 & 1023;
        if (which == 2) {
#pragma unroll
            for (int mi = 0; mi < 4; ++mi) {
                const int m = m0 + wm * 64 + mi * 16 + quad * 4;
                const int b = m >> 11, t = m & 2047;
#pragma unroll
                for (int ni = 0; ni < 4; ++ni) {
                    const int n = nb + wn * 64 + ni * 16 + c;
                    const int h = n >> 6, d = n & 63;
                    short4 s4 = make_short4(f2bf(acc[mi][ni][0]), f2bf(acc[mi][ni][1]),
                                            f2bf(acc[mi][ni][2]), f2bf(acc[mi][ni][3]));
                    *(short4*)(vo + (((size_t)b * H_ + h) * D_ + d) * T_ + t) = s4;
                }
            }
        } else {
            short* __restrict__ outp = (which == 0) ? qo : ko;
            const float sc = (which == 0) ? 0.18033688f : 1.0f;
#pragma unroll
            for (int mi = 0; mi < 4; ++mi) {
#pragma unroll
                for (int i = 0; i < 4; ++i) {
                    const int m = m0 + wm * 64 + mi * 16 + quad * 4 + i;
                    const int b = m >> 11, t = m & 2047;
#pragma unroll
                    for (int ni = 0; ni < 4; ++ni) {
                        const int n = nb + wn * 64 + ni * 16 + c;
                        const int h = n >> 6, d = n & 63;
                        outp[(((size_t)b * H_ + h) * T_ + t) * D_ + d] =
                            f2bf(acc[mi][ni][i] * sc);
                    }
                }
            }
        }
    } else {
#pragma unroll
        for (int mi = 0; mi < 4; ++mi) {
#pragma unroll
            for (int i = 0; i < 4; ++i) {
                const int m = m0 + wm * 64 + mi * 16 + quad * 4 + i;
#pragma unroll
                for (int ni = 0; ni < 4; ++ni) {
                    const int n = n0 + wn * 64 + ni * 16 + c;
                    Cout[(size_t)m * E_ + n] = acc[mi][ni][i] + bo[n];
                }
            }
        }
    }
}

// ---------------------------------------------------------------------------
// Flash attention v8 (R9): per-tile compute identical to v7, but the tile
// loop processes PAIRS of KV tiles per iteration. The two chains are fully
// independent -> dual-issue ILP hides each chain's MFMA/exp2 latency, and
// barrier+vmcnt crossings halve.
//
// Iter j (tiles 2j, 2j+1):  vmcnt(0) [prev iter's 4 stage loads had a full
// iter to land]; barrier [all waves' loads visible + all reads of the stage
// target bufs done]; STAGE(2j+2), STAGE(2j+3) [bufs (2j+2)&3,(2j+3)&3 --
// disjoint from read bufs (2j)&3,(2j+1)&3]; compute both tiles.
// nt = 4kb+4 is always even.
// ---------------------------------------------------------------------------
__device__ __forceinline__ void attn_tile(
        const int tt, const int mytile, const char* __restrict__ lds,
        const int ln, const int hi, const bf16x8* __restrict__ qf,
        const int4 ka4, const int4 va4,
        f32x16& O0, f32x16& O1, float& lacc) {
    if (tt > mytile) return;
    const int s0 = tt << 5;
    const int bb = (tt & 3) * 8192;
    const int ka[4] = {ka4.x, ka4.y, ka4.z, ka4.w};
    const int va[4] = {va4.x, va4.y, va4.z, va4.w};

    f32x4 b4[4];
#pragma unroll
    for (int g = 0; g < 4; ++g)
        b4[g] = *(const f32x4*)(lds + 32768 + (s0 + g * 8 + hi * 4) * 4);

    f32x16 S = {};
    __builtin_amdgcn_s_setprio(1);
#pragma unroll
    for (int kc = 0; kc < 4; ++kc) {
        bf16x8 kv = *(const bf16x8*)(lds + bb + ka[kc]);
        S = __builtin_amdgcn_mfma_f32_32x32x16_bf16(kv, qf[kc], S, 0, 0, 0);
    }
    __builtin_amdgcn_s_setprio(0);

    float p[16];
#pragma unroll
    for (int r = 0; r < 16; ++r) {
        float bb2 = ((const float*)&b4[r >> 2])[r & 3];
        p[r] = __builtin_amdgcn_exp2f(S[r] + bb2);
    }
    if (tt == mytile) {                            // causal mask on diagonal
#pragma unroll
        for (int r = 0; r < 16; ++r)
            if (((r & 3) + ((r >> 2) << 3) + (hi << 2)) > ln)
                p[r] = 0.0f;
    }
    {
        float t0 = (p[0] + p[1]) + (p[2] + p[3]);
        float t1 = (p[4] + p[5]) + (p[6] + p[7]);
        float t2s = (p[8] + p[9]) + (p[10] + p[11]);
        float t3 = (p[12] + p[13]) + (p[14] + p[15]);
        lacc += (t0 + t1) + (t2s + t3);
    }

    unsigned int u0, u1, u2, u3, u4, u5, u6, u7;
    asm("v_cvt_pk_bf16_f32 %0, %1, %2" : "=v"(u0) : "v"(p[0]),  "v"(p[1]));
    asm("v_cvt_pk_bf16_f32 %0, %1, %2" : "=v"(u1) : "v"(p[2]),  "v"(p[3]));
    asm("v_cvt_pk_bf16_f32 %0, %1, %2" : "=v"(u2) : "v"(p[4]),  "v"(p[5]));
    asm("v_cvt_pk_bf16_f32 %0, %1, %2" : "=v"(u3) : "v"(p[6]),  "v"(p[7]));
    asm("v_cvt_pk_bf16_f32 %0, %1, %2" : "=v"(u4) : "v"(p[8]),  "v"(p[9]));
    asm("v_cvt_pk_bf16_f32 %0, %1, %2" : "=v"(u5) : "v"(p[10]), "v"(p[11]));
    asm("v_cvt_pk_bf16_f32 %0, %1, %2" : "=v"(u6) : "v"(p[12]), "v"(p[13]));
    asm("v_cvt_pk_bf16_f32 %0, %1, %2" : "=v"(u7) : "v"(p[14]), "v"(p[15]));
    asm("v_permlane32_swap_b32 %0, %1" : "+v"(u0), "+v"(u2));
    asm("v_permlane32_swap_b32 %0, %1" : "+v"(u1), "+v"(u3));
    asm("v_permlane32_swap_b32 %0, %1" : "+v"(u4), "+v"(u6));
    asm("v_permlane32_swap_b32 %0, %1" : "+v"(u5), "+v"(u7));
    union { unsigned int w[4]; bf16x8 v; } pa0, pa1;
    pa0.w[0] = u0; pa0.w[1] = u1; pa0.w[2] = u2; pa0.w[3] = u3;
    pa1.w[0] = u4; pa1.w[1] = u5; pa1.w[2] = u6; pa1.w[3] = u7;

    bf16x8 v00 = *(const bf16x8*)(lds + bb + va[0]);
    bf16x8 v01 = *(const bf16x8*)(lds + bb + va[1]);
    bf16x8 v10 = *(const bf16x8*)(lds + bb + va[2]);
    bf16x8 v11 = *(const bf16x8*)(lds + bb + va[3]);
    __builtin_amdgcn_s_setprio(1);
    O0 = __builtin_amdgcn_mfma_f32_32x32x16_bf16(pa0.v, v00, O0, 0, 0, 0);
    O0 = __builtin_amdgcn_mfma_f32_32x32x16_bf16(pa1.v, v01, O0, 0, 0, 0);
    O1 = __builtin_amdgcn_mfma_f32_32x32x16_bf16(pa0.v, v10, O1, 0, 0, 0);
    O1 = __builtin_amdgcn_mfma_f32_32x32x16_bf16(pa1.v, v11, O1, 0, 0, 0);
    __builtin_amdgcn_s_setprio(0);
}

__global__ __launch_bounds__(256, 4) void flash_attn8(
        const short* __restrict__ qg,
        const short* __restrict__ kg,
        const short* __restrict__ vtg,
        const float* __restrict__ biasg,
        short* __restrict__ attn) {
    const int h = blockIdx.x, b = blockIdx.y;
    const int kb = 15 - blockIdx.z;                // 128-row q block, heavy first
    const int tid  = threadIdx.x;
    const int wave = tid >> 6, lane = tid & 63;
    const int ln = lane & 31, hi = lane >> 5;
    const int q0w = kb * 128 + wave * 32;          // this wave's 32 q rows
    const int mytile = 4 * kb + wave;              // wave's diagonal tile
    const int nt = 4 * kb + 4;                     // even
    const int np = nt >> 1;

    __shared__ __align__(16) char lds[40960];

    const size_t bh = (size_t)b * H_ + h;
    const short* qbh  = qg  + bh * (size_t)T_ * D_;
    const short* kbh  = kg  + bh * (size_t)T_ * D_;
    const short* vtbh = vtg + bh * (size_t)D_ * T_;
    const float* biasb = biasg + (size_t)b * T_;

    const int ks = tid >> 3, kgs = (tid & 7) ^ (ks & 7);        // K row / src chunk
    const int vd = tid >> 2, vgs = ((tid & 3) - (vd >> 1)) & 3; // V row / src chunk

    int4 ka4, va4;
    {
        int tmp[4];
#pragma unroll
        for (int kc = 0; kc < 4; ++kc)
            tmp[kc] = ln * 128 + ((((kc << 1) + hi) ^ (ln & 7)) << 4);
        ka4 = make_int4(tmp[0], tmp[1], tmp[2], tmp[3]);
#pragma unroll
        for (int dh = 0; dh < 2; ++dh)
#pragma unroll
            for (int kc2 = 0; kc2 < 2; ++kc2) {
                int d = dh * 32 + ln;
                tmp[dh * 2 + kc2] =
                    4096 + d * 64 + (((((kc2 << 1) + hi) + (d >> 1)) & 3) << 4);
            }
        va4 = make_int4(tmp[0], tmp[1], tmp[2], tmp[3]);
    }

    bf16x8 qf[4];
#pragma unroll
    for (int kc = 0; kc < 4; ++kc)
        qf[kc] = *(const bf16x8*)(qbh + (size_t)(q0w + ln) * D_ + kc * 16 + hi * 8);

    // stage bias[0..2047] -> LDS once
#pragma unroll
    for (int r = 0; r < 2; ++r)
        async_ld16(biasb + r * 1024 + tid * 4,
                   lds + 32768 + r * 4096 + wave * 1024);

#define STAGE_T(tt2) do {                                                   \
        const int _s0 = (tt2) << 5;                                         \
        const int _bb = ((tt2) & 3) * 8192;                                 \
        async_ld16(kbh + (size_t)(_s0 + ks) * D_ + (kgs << 3),              \
                   lds + _bb + wave * 1024);                                \
        async_ld16(vtbh + (size_t)vd * T_ + _s0 + (vgs << 3),               \
                   lds + _bb + 4096 + wave * 1024);                         \
    } while (0)

    STAGE_T(0);
    STAGE_T(1);

    f32x16 O0 = {}, O1 = {};
    float lacc = 0.0f;

#pragma unroll 1
    for (int j = 0; j < np; ++j) {
        asm volatile("s_waitcnt vmcnt(0)" ::: "memory");
        __builtin_amdgcn_s_barrier();              // tiles 2j,2j+1 visible; old reads done
        if (j + 1 < np) { STAGE_T(2 * j + 2); STAGE_T(2 * j + 3); }

        attn_tile(2 * j,     mytile, lds, ln, hi, qf, ka4, va4, O0, O1, lacc);
        attn_tile(2 * j + 1, mytile, lds, ln, hi, qf, ka4, va4, O0, O1, lacc);
    }
#undef STAGE_T

    // ---- epilogue: combine l across hi-halves, normalize, store -----------
    unsigned int la = __float_as_uint(lacc), lb2 = la;
    asm("v_permlane32_swap_b32 %0, %1" : "+v"(la), "+v"(lb2));
    const float ltot = __uint_as_float(la) + __uint_as_float(lb2);

    __syncthreads();                               // all buf reads done
    float* lsh = (float*)lds + wave * 32;          // overlay buffer 0
    if (hi == 0) lsh[ln] = 1.0f / ltot;
    __syncthreads();

    short* ab = attn + (size_t)b * T_ * E_ + h * D_;
#pragma unroll
    for (int r = 0; r < 16; ++r) {
        const int qrow = (r & 3) + ((r >> 2) << 3) + (hi << 2);
        const float iv = lsh[qrow];
        const size_t base = (size_t)(q0w + qrow) * E_;
        ab[base + ln]      = f2bf(O0[r] * iv);
        ab[base + 32 + ln] = f2bf(O1[r] * iv);
    }
}

// ---------------------------------------------------------------------------
extern "C" void kernel_launch(void* const* d_in, const int* in_sizes, int n_in,
                              void* d_out, int out_size, void* d_ws, size_t ws_size,
                              hipStream_t stream) {
    const float* x    = (const float*)d_in[0];
    const float* mask = (const float*)d_in[1];
    const float* Wq   = (const float*)d_in[2];
    const float* Wk   = (const float*)d_in[3];
    const float* Wv   = (const float*)d_in[4];
    const float* Wo   = (const float*)d_in[5];
    const float* bo   = (const float*)d_in[6];
    float* out        = (float*)d_out;

    const size_t S = (size_t)M_ * E_;              // 8.4M elems
    char* ws = (char*)d_ws;
    short* xb   = (short*)ws;                      // bf16 x; reused as attn
    short* qb   = (short*)(ws + S * 2);
    short* kb   = (short*)(ws + S * 4);
    short* vtb  = (short*)(ws + S * 6);            // V stored transposed by MODE0
    short* Wt   = (short*)(ws + S * 8);
    short* Wob  = (short*)(ws + S * 8 + (size_t)3 * 1024 * 1024 * 2);
    float* bias = (float*)(ws + S * 8 + (size_t)4 * 1024 * 1024 * 2);
    short* attnb = xb;

    prep_fused<<<dim3(10016), 256, 0, stream>>>(
        x, Wo, Wq, Wk, Wv, mask, xb, Wob, Wt, bias);

    mfma_gemm<0><<<dim3(M_ / 256, 3 * E_ / 128), 512, 0, stream>>>(
        xb, Wt, qb, kb, vtb, nullptr, nullptr);

    flash_attn8<<<dim3(H_, B_, 16), 256, 0, stream>>>(qb, kb, vtb, bias, attnb);

    mfma_gemm<1><<<dim3(M_ / 256, E_ / 128), 512, 0, stream>>>(
        attnb, Wob, nullptr, nullptr, nullptr, out, bo);
}

// Round 10
// 225.667 us; speedup vs baseline: 1.1123x; 1.1123x over previous
//
#include <hip/hip_runtime.h>
#include <hip/hip_bf16.h>

#define B_ 4
#define T_ 2048
#define E_ 1024
#define H_ 16
#define D_ 64
#define M_ (B_*T_)   // 8192 rows

typedef short bf16x8 __attribute__((ext_vector_type(8)));
typedef float f32x4  __attribute__((ext_vector_type(4)));
typedef float f32x16 __attribute__((ext_vector_type(16)));

__device__ __forceinline__ short f2bf(float f) {
    __hip_bfloat16 h = __float2bfloat16(f);
    return *reinterpret_cast<short*>(&h);
}

__device__ __forceinline__ void async_ld16(const void* g, void* l) {
    __builtin_amdgcn_global_load_lds(
        (const __attribute__((address_space(1))) unsigned int*)g,
        (__attribute__((address_space(3))) unsigned int*)l, 16, 0, 0);
}

// ---------------------------------------------------------------------------
// Fused prep kernel (R8, unchanged).
// ---------------------------------------------------------------------------
__global__ __launch_bounds__(256) void prep_fused(
        const float* __restrict__ x,   const float* __restrict__ Wo,
        const float* __restrict__ Wq,  const float* __restrict__ Wk,
        const float* __restrict__ Wv,  const float* __restrict__ mask,
        short* __restrict__ xb, short* __restrict__ Wob,
        short* __restrict__ Wt, float* __restrict__ bias) {
    __shared__ float tile[64][65];
    const int bi  = blockIdx.x;
    const int tid = threadIdx.x;

    if (bi < 9216) {                               // elementwise fp32->bf16
        const float* src = (bi < 8192) ? x : Wo;
        short* dst       = (bi < 8192) ? xb : Wob;
        const int i = ((bi < 8192) ? bi : (bi - 8192)) * 256 + tid;
        float4 v = ((const float4*)src)[i];
        short4 o = make_short4(f2bf(v.x), f2bf(v.y), f2bf(v.z), f2bf(v.w));
        ((short4*)dst)[i] = o;
    } else if (bi < 9984) {                        // weight transpose
        const int idx = bi - 9216;
        const int which = idx >> 8;                // 0..2
        const int h  = (idx & 255) >> 4;
        const int e0 = (idx & 15) * 64;
        const float* __restrict__ W = (which == 0) ? Wq : (which == 1) ? Wk : Wv;
#pragma unroll
        for (int r = 0; r < 4; ++r) {
            int lin = tid + r * 256;
            int er = lin >> 4, c4 = (lin & 15) * 4;
            float4 v = *(const float4*)(W + ((size_t)h * E_ + e0 + er) * D_ + c4);
            tile[er][c4 + 0] = v.x; tile[er][c4 + 1] = v.y;
            tile[er][c4 + 2] = v.z; tile[er][c4 + 3] = v.w;
        }
        __syncthreads();
#pragma unroll
        for (int r = 0; r < 4; ++r) {
            int lin = tid + r * 256;
            int dr = lin >> 4, j4 = (lin & 15) * 4;
            short4 o = make_short4(f2bf(tile[j4 + 0][dr]), f2bf(tile[j4 + 1][dr]),
                                   f2bf(tile[j4 + 2][dr]), f2bf(tile[j4 + 3][dr]));
            *(short4*)(Wt + ((size_t)which * 1024 + h * 64 + dr) * E_ + e0 + j4) = o;
        }
    } else {                                       // bias prep
        const int i = (bi - 9984) * 256 + tid;
        float bm = (1.0f - mask[i]) * -3.402823466e38f;
        bias[i] = fmaf(bm, 1.4426950f, -8.6561700f);
    }
}

// ---------------------------------------------------------------------------
// MFMA GEMM v4 (R8 schedule; R10 reverts the R9 XCD swizzle — it QUADRUPLED
// FETCH_SIZE on this L3-resident problem, per guide T1 "costs when L3-fit").
// BK=32, 3 x 24KB LDS buffers -> 2 blocks/CU. Single-barrier counted-vmcnt:
//   iter k: stage(k+2) [3 loads] -> 8 ds_read -> 16 MFMA (setprio)
//           -> vmcnt(3) -> barrier.
// ---------------------------------------------------------------------------
template <int MODE>
__global__ __launch_bounds__(512, 4) void mfma_gemm(
        const short* __restrict__ A,
        const short* __restrict__ Bt,
        short* __restrict__ qo, short* __restrict__ ko, short* __restrict__ vo,
        float* __restrict__ Cout, const float* __restrict__ bo) {
    __shared__ __align__(16) char lds[3 * 24576];   // 72 KiB -> 2 blocks/CU

    const int tid  = threadIdx.x;
    const int wave = tid >> 6, lane = tid & 63;
    const int c = lane & 15, quad = lane >> 4;
    const int wm = wave >> 1, wn = wave & 1;        // 4M x 2N
    const int m0 = blockIdx.x * 256;
    const int n0 = blockIdx.y * 128;

    const int ar = tid >> 2;
    const int ag = (tid & 3) ^ ((tid >> 3) & 3);

    int aoff[4], boff[4];
#pragma unroll
    for (int mi = 0; mi < 4; ++mi) {
        int row = wm * 64 + mi * 16 + c;
        aoff[mi] = row * 64 + ((quad ^ ((row >> 1) & 3)) << 4);
    }
#pragma unroll
    for (int ni = 0; ni < 4; ++ni) {
        int row = wn * 64 + ni * 16 + c;
        boff[ni] = 16384 + row * 64 + ((quad ^ ((row >> 1) & 3)) << 4);
    }

    f32x4 acc[4][4] = {};

#define STG(bufb, k0v) do {                                                  \
        async_ld16(A  + (size_t)(m0 + ar) * 1024 + (k0v) + ag * 8,           \
                   lds + (bufb) + wave * 1024);                              \
        async_ld16(A  + (size_t)(m0 + 128 + ar) * 1024 + (k0v) + ag * 8,     \
                   lds + (bufb) + 8192 + wave * 1024);                       \
        async_ld16(Bt + (size_t)(n0 + ar) * 1024 + (k0v) + ag * 8,           \
                   lds + (bufb) + 16384 + wave * 1024);                      \
    } while (0)

    STG(0, 0);
    STG(24576, 32);
    asm volatile("s_waitcnt vmcnt(3)" ::: "memory");   // K-tile 0 landed
    __builtin_amdgcn_s_barrier();

    int rbase = 0;
#pragma unroll 1
    for (int k = 0; k < 32; ++k) {
        const char* rb = lds + rbase;
        const int wbase = (rbase == 0) ? 49152 : rbase - 24576;

        if (k < 30) STG(wbase, (k + 2) * 32);

        bf16x8 a_[4], b_[4];
#pragma unroll
        for (int mi = 0; mi < 4; ++mi)
            a_[mi] = *(const bf16x8*)(rb + aoff[mi]);
#pragma unroll
        for (int ni = 0; ni < 4; ++ni)
            b_[ni] = *(const bf16x8*)(rb + boff[ni]);

        __builtin_amdgcn_s_setprio(1);
#pragma unroll
        for (int mi = 0; mi < 4; ++mi)
#pragma unroll
            for (int ni = 0; ni < 4; ++ni)
                acc[mi][ni] = __builtin_amdgcn_mfma_f32_16x16x32_bf16(
                    a_[mi], b_[ni], acc[mi][ni], 0, 0, 0);
        __builtin_amdgcn_s_setprio(0);

        if (k < 30)       asm volatile("s_waitcnt vmcnt(3)" ::: "memory");
        else if (k == 30) asm volatile("s_waitcnt vmcnt(0)" ::: "memory");
        if (k < 31) __builtin_amdgcn_s_barrier();

        rbase = (rbase == 49152) ? 0 : rbase + 24576;
    }
#undef STG

    if (MODE == 0) {
        const int which = n0 >> 10;
        const int nb = n0 & 1023;
        if (which == 2) {
#pragma unroll
            for (int mi = 0; mi < 4; ++mi) {
                const int m = m0 + wm * 64 + mi * 16 + quad * 4;
                const int b = m >> 11, t = m & 2047;
#pragma unroll
                for (int ni = 0; ni < 4; ++ni) {
                    const int n = nb + wn * 64 + ni * 16 + c;
                    const int h = n >> 6, d = n & 63;
                    short4 s4 = make_short4(f2bf(acc[mi][ni][0]), f2bf(acc[mi][ni][1]),
                                            f2bf(acc[mi][ni][2]), f2bf(acc[mi][ni][3]));
                    *(short4*)(vo + (((size_t)b * H_ + h) * D_ + d) * T_ + t) = s4;
                }
            }
        } else {
            short* __restrict__ outp = (which == 0) ? qo : ko;
            const float sc = (which == 0) ? 0.18033688f : 1.0f;
#pragma unroll
            for (int mi = 0; mi < 4; ++mi) {
#pragma unroll
                for (int i = 0; i < 4; ++i) {
                    const int m = m0 + wm * 64 + mi * 16 + quad * 4 + i;
                    const int b = m >> 11, t = m & 2047;
#pragma unroll
                    for (int ni = 0; ni < 4; ++ni) {
                        const int n = nb + wn * 64 + ni * 16 + c;
                        const int h = n >> 6, d = n & 63;
                        outp[(((size_t)b * H_ + h) * T_ + t) * D_ + d] =
                            f2bf(acc[mi][ni][i] * sc);
                    }
                }
            }
        }
    } else {
#pragma unroll
        for (int mi = 0; mi < 4; ++mi) {
#pragma unroll
            for (int i = 0; i < 4; ++i) {
                const int m = m0 + wm * 64 + mi * 16 + quad * 4 + i;
#pragma unroll
                for (int ni = 0; ni < 4; ++ni) {
                    const int n = n0 + wn * 64 + ni * 16 + c;
                    Cout[(size_t)m * E_ + n] = acc[mi][ni][i] + bo[n];
                }
            }
        }
    }
}

// ---------------------------------------------------------------------------
// Flash attention v8 (R9, kept): pair-of-tiles per iteration for dual-chain
// ILP; per-tile compute identical to the verified v7.
// ---------------------------------------------------------------------------
__device__ __forceinline__ void attn_tile(
        const int tt, const int mytile, const char* __restrict__ lds,
        const int ln, const int hi, const bf16x8* __restrict__ qf,
        const int4 ka4, const int4 va4,
        f32x16& O0, f32x16& O1, float& lacc) {
    if (tt > mytile) return;
    const int s0 = tt << 5;
    const int bb = (tt & 3) * 8192;
    const int ka[4] = {ka4.x, ka4.y, ka4.z, ka4.w};
    const int va[4] = {va4.x, va4.y, va4.z, va4.w};

    f32x4 b4[4];
#pragma unroll
    for (int g = 0; g < 4; ++g)
        b4[g] = *(const f32x4*)(lds + 32768 + (s0 + g * 8 + hi * 4) * 4);

    f32x16 S = {};
    __builtin_amdgcn_s_setprio(1);
#pragma unroll
    for (int kc = 0; kc < 4; ++kc) {
        bf16x8 kv = *(const bf16x8*)(lds + bb + ka[kc]);
        S = __builtin_amdgcn_mfma_f32_32x32x16_bf16(kv, qf[kc], S, 0, 0, 0);
    }
    __builtin_amdgcn_s_setprio(0);

    float p[16];
#pragma unroll
    for (int r = 0; r < 16; ++r) {
        float bb2 = ((const float*)&b4[r >> 2])[r & 3];
        p[r] = __builtin_amdgcn_exp2f(S[r] + bb2);
    }
    if (tt == mytile) {                            // causal mask on diagonal
#pragma unroll
        for (int r = 0; r < 16; ++r)
            if (((r & 3) + ((r >> 2) << 3) + (hi << 2)) > ln)
                p[r] = 0.0f;
    }
    {
        float t0 = (p[0] + p[1]) + (p[2] + p[3]);
        float t1 = (p[4] + p[5]) + (p[6] + p[7]);
        float t2s = (p[8] + p[9]) + (p[10] + p[11]);
        float t3 = (p[12] + p[13]) + (p[14] + p[15]);
        lacc += (t0 + t1) + (t2s + t3);
    }

    unsigned int u0, u1, u2, u3, u4, u5, u6, u7;
    asm("v_cvt_pk_bf16_f32 %0, %1, %2" : "=v"(u0) : "v"(p[0]),  "v"(p[1]));
    asm("v_cvt_pk_bf16_f32 %0, %1, %2" : "=v"(u1) : "v"(p[2]),  "v"(p[3]));
    asm("v_cvt_pk_bf16_f32 %0, %1, %2" : "=v"(u2) : "v"(p[4]),  "v"(p[5]));
    asm("v_cvt_pk_bf16_f32 %0, %1, %2" : "=v"(u3) : "v"(p[6]),  "v"(p[7]));
    asm("v_cvt_pk_bf16_f32 %0, %1, %2" : "=v"(u4) : "v"(p[8]),  "v"(p[9]));
    asm("v_cvt_pk_bf16_f32 %0, %1, %2" : "=v"(u5) : "v"(p[10]), "v"(p[11]));
    asm("v_cvt_pk_bf16_f32 %0, %1, %2" : "=v"(u6) : "v"(p[12]), "v"(p[13]));
    asm("v_cvt_pk_bf16_f32 %0, %1, %2" : "=v"(u7) : "v"(p[14]), "v"(p[15]));
    asm("v_permlane32_swap_b32 %0, %1" : "+v"(u0), "+v"(u2));
    asm("v_permlane32_swap_b32 %0, %1" : "+v"(u1), "+v"(u3));
    asm("v_permlane32_swap_b32 %0, %1" : "+v"(u4), "+v"(u6));
    asm("v_permlane32_swap_b32 %0, %1" : "+v"(u5), "+v"(u7));
    union { unsigned int w[4]; bf16x8 v; } pa0, pa1;
    pa0.w[0] = u0; pa0.w[1] = u1; pa0.w[2] = u2; pa0.w[3] = u3;
    pa1.w[0] = u4; pa1.w[1] = u5; pa1.w[2] = u6; pa1.w[3] = u7;

    bf16x8 v00 = *(const bf16x8*)(lds + bb + va[0]);
    bf16x8 v01 = *(const bf16x8*)(lds + bb + va[1]);
    bf16x8 v10 = *(const bf16x8*)(lds + bb + va[2]);
    bf16x8 v11 = *(const bf16x8*)(lds + bb + va[3]);
    __builtin_amdgcn_s_setprio(1);
    O0 = __builtin_amdgcn_mfma_f32_32x32x16_bf16(pa0.v, v00, O0, 0, 0, 0);
    O0 = __builtin_amdgcn_mfma_f32_32x32x16_bf16(pa1.v, v01, O0, 0, 0, 0);
    O1 = __builtin_amdgcn_mfma_f32_32x32x16_bf16(pa0.v, v10, O1, 0, 0, 0);
    O1 = __builtin_amdgcn_mfma_f32_32x32x16_bf16(pa1.v, v11, O1, 0, 0, 0);
    __builtin_amdgcn_s_setprio(0);
}

__global__ __launch_bounds__(256, 4) void flash_attn8(
        const short* __restrict__ qg,
        const short* __restrict__ kg,
        const short* __restrict__ vtg,
        const float* __restrict__ biasg,
        short* __restrict__ attn) {
    const int h = blockIdx.x, b = blockIdx.y;
    const int kb = 15 - blockIdx.z;                // 128-row q block, heavy first
    const int tid  = threadIdx.x;
    const int wave = tid >> 6, lane = tid & 63;
    const int ln = lane & 31, hi = lane >> 5;
    const int q0w = kb * 128 + wave * 32;          // this wave's 32 q rows
    const int mytile = 4 * kb + wave;              // wave's diagonal tile
    const int nt = 4 * kb + 4;                     // even
    const int np = nt >> 1;

    __shared__ __align__(16) char lds[40960];

    const size_t bh = (size_t)b * H_ + h;
    const short* qbh  = qg  + bh * (size_t)T_ * D_;
    const short* kbh  = kg  + bh * (size_t)T_ * D_;
    const short* vtbh = vtg + bh * (size_t)D_ * T_;
    const float* biasb = biasg + (size_t)b * T_;

    const int ks = tid >> 3, kgs = (tid & 7) ^ (ks & 7);        // K row / src chunk
    const int vd = tid >> 2, vgs = ((tid & 3) - (vd >> 1)) & 3; // V row / src chunk

    int4 ka4, va4;
    {
        int tmp[4];
#pragma unroll
        for (int kc = 0; kc < 4; ++kc)
            tmp[kc] = ln * 128 + ((((kc << 1) + hi) ^ (ln & 7)) << 4);
        ka4 = make_int4(tmp[0], tmp[1], tmp[2], tmp[3]);
#pragma unroll
        for (int dh = 0; dh < 2; ++dh)
#pragma unroll
            for (int kc2 = 0; kc2 < 2; ++kc2) {
                int d = dh * 32 + ln;
                tmp[dh * 2 + kc2] =
                    4096 + d * 64 + (((((kc2 << 1) + hi) + (d >> 1)) & 3) << 4);
            }
        va4 = make_int4(tmp[0], tmp[1], tmp[2], tmp[3]);
    }

    bf16x8 qf[4];
#pragma unroll
    for (int kc = 0; kc < 4; ++kc)
        qf[kc] = *(const bf16x8*)(qbh + (size_t)(q0w + ln) * D_ + kc * 16 + hi * 8);

    // stage bias[0..2047] -> LDS once
#pragma unroll
    for (int r = 0; r < 2; ++r)
        async_ld16(biasb + r * 1024 + tid * 4,
                   lds + 32768 + r * 4096 + wave * 1024);

#define STAGE_T(tt2) do {                                                   \
        const int _s0 = (tt2) << 5;                                         \
        const int _bb = ((tt2) & 3) * 8192;                                 \
        async_ld16(kbh + (size_t)(_s0 + ks) * D_ + (kgs << 3),              \
                   lds + _bb + wave * 1024);                                \
        async_ld16(vtbh + (size_t)vd * T_ + _s0 + (vgs << 3),               \
                   lds + _bb + 4096 + wave * 1024);                         \
    } while (0)

    STAGE_T(0);
    STAGE_T(1);

    f32x16 O0 = {}, O1 = {};
    float lacc = 0.0f;

#pragma unroll 1
    for (int j = 0; j < np; ++j) {
        asm volatile("s_waitcnt vmcnt(0)" ::: "memory");
        __builtin_amdgcn_s_barrier();              // tiles 2j,2j+1 visible; old reads done
        if (j + 1 < np) { STAGE_T(2 * j + 2); STAGE_T(2 * j + 3); }

        attn_tile(2 * j,     mytile, lds, ln, hi, qf, ka4, va4, O0, O1, lacc);
        attn_tile(2 * j + 1, mytile, lds, ln, hi, qf, ka4, va4, O0, O1, lacc);
    }
#undef STAGE_T

    // ---- epilogue: combine l across hi-halves, normalize, store -----------
    unsigned int la = __float_as_uint(lacc), lb2 = la;
    asm("v_permlane32_swap_b32 %0, %1" : "+v"(la), "+v"(lb2));
    const float ltot = __uint_as_float(la) + __uint_as_float(lb2);

    __syncthreads();                               // all buf reads done
    float* lsh = (float*)lds + wave * 32;          // overlay buffer 0
    if (hi == 0) lsh[ln] = 1.0f / ltot;
    __syncthreads();

    short* ab = attn + (size_t)b * T_ * E_ + h * D_;
#pragma unroll
    for (int r = 0; r < 16; ++r) {
        const int qrow = (r & 3) + ((r >> 2) << 3) + (hi << 2);
        const float iv = lsh[qrow];
        const size_t base = (size_t)(q0w + qrow) * E_;
        ab[base + ln]      = f2bf(O0[r] * iv);
        ab[base + 32 + ln] = f2bf(O1[r] * iv);
    }
}

// ---------------------------------------------------------------------------
extern "C" void kernel_launch(void* const* d_in, const int* in_sizes, int n_in,
                              void* d_out, int out_size, void* d_ws, size_t ws_size,
                              hipStream_t stream) {
    const float* x    = (const float*)d_in[0];
    const float* mask = (const float*)d_in[1];
    const float* Wq   = (const float*)d_in[2];
    const float* Wk   = (const float*)d_in[3];
    const float* Wv   = (const float*)d_in[4];
    const float* Wo   = (const float*)d_in[5];
    const float* bo   = (const float*)d_in[6];
    float* out        = (float*)d_out;

    const size_t S = (size_t)M_ * E_;              // 8.4M elems
    char* ws = (char*)d_ws;
    short* xb   = (short*)ws;                      // bf16 x; reused as attn
    short* qb   = (short*)(ws + S * 2);
    short* kb   = (short*)(ws + S * 4);
    short* vtb  = (short*)(ws + S * 6);            // V stored transposed by MODE0
    short* Wt   = (short*)(ws + S * 8);
    short* Wob  = (short*)(ws + S * 8 + (size_t)3 * 1024 * 1024 * 2);
    float* bias = (float*)(ws + S * 8 + (size_t)4 * 1024 * 1024 * 2);
    short* attnb = xb;

    prep_fused<<<dim3(10016), 256, 0, stream>>>(
        x, Wo, Wq, Wk, Wv, mask, xb, Wob, Wt, bias);

    mfma_gemm<0><<<dim3(M_ / 256, 3 * E_ / 128), 512, 0, stream>>>(
        xb, Wt, qb, kb, vtb, nullptr, nullptr);

    flash_attn8<<<dim3(H_, B_, 16), 256, 0, stream>>>(qb, kb, vtb, bias, attnb);

    mfma_gemm<1><<<dim3(M_ / 256, E_ / 128), 512, 0, stream>>>(
        attnb, Wob, nullptr, nullptr, nullptr, out, bo);
}